// Round 16
// baseline (262.818 us; speedup 1.0000x reference)
//
#include <hip/hip_runtime.h>

typedef short short8  __attribute__((ext_vector_type(8)));
typedef float f32x4   __attribute__((ext_vector_type(4)));
typedef float f32x16  __attribute__((ext_vector_type(16)));

#define MFMA32(A,B,C) __builtin_amdgcn_mfma_f32_32x32x16_bf16((A),(B),(C),0,0,0)

__device__ __forceinline__ short bf16bits(float f){
  return (short)__builtin_bit_cast(unsigned short, static_cast<__bf16>(f));
}

// exp(s*0.125 - 8) = exp2(s*0.125*log2e - 8*log2e): one v_fma + v_exp.
// Region mask folded into BIAS: -3e38 -> exp2 == 0 exactly.
#define EXP_SCORE(s, BIAS) __builtin_amdgcn_exp2f(__builtin_fmaf((s), 0.18033688011112042f, (BIAS)))
#define EXP_C2 (-11.541560327111707f)

// ---------------- fused preprocessing ----------------
// blocks [0,220): mask preprocessing  (region_masks -> allowed bits)
// blocks [220,988): K/V repack to bf16 for the 32x32x16 MFMA path.
// All fragment chunks are 1KB = 64 lanes x 16B, lane l at offset l*16
// (fully-coalesced global_load_dwordx4 by construction).
//   K chunk (kc=key/32, f=d/16): lane = ((d>>3)&1)*32 + (key&31),
//     elem j = d&7  -> holds K[key][d = f*16 + 8*hi + j].
//   V chunk (kc, dblk=d/32, kh): key slot sigma-permuted so the score
//     MFMA's C register file IS the PV B-operand (no P anywhere):
//     C row formula row=(r&3)+8*(r>>2)+4*hi  =>  slot (kh,hi,e) must hold
//     key kappa = 16*kh + (e&3) + 8*(e>>2) + 4*hi. Inverse (given kappa):
//     kh=kappa>>4; rem=kappa&15; hi=(rem>>2)&1; e=(rem&3)+4*(rem>>3).
// (Layouts verified on hardware in rounds 14/15: passed, same absmax.)
__global__ __launch_bounds__(256) void prep_kernel(const float* __restrict__ rm,
                                                   const float* __restrict__ k,
                                                   const float* __restrict__ v,
                                                   const float* __restrict__ rk,
                                                   const float* __restrict__ rv,
                                                   unsigned* __restrict__ allowed,
                                                   unsigned short* __restrict__ Kb,
                                                   unsigned short* __restrict__ VT){
  const int bid = blockIdx.x;
  if (bid < 220){
    int s = bid*256 + threadIdx.x;
    if (s >= 56320) return;
    int t = s / 3520;
    int rem = s - t*3520;
    int i = rem / 80;
    int j = rem - i*80;
    int y = 2*i, x = 2*j;
    bool bin[2];
    #pragma unroll
    for (int r=0;r<2;r++){
      const float* base = rm + (size_t)r*121*88*160;
      float acc;
      if (t == 0){
        const float* p0 = base + (size_t)(0*88 + y)*160 + x;
        acc = 0.25f*(p0[0]+p0[1]+p0[160]+p0[161]);
      } else {
        const float* pa = base + (size_t)((8*t-4)*88 + y)*160 + x;
        const float* pb = base + (size_t)((8*t-3)*88 + y)*160 + x;
        acc = 0.125f*(pa[0]+pa[1]+pa[160]+pa[161] + pb[0]+pb[1]+pb[160]+pb[161]);
      }
      bin[r] = acc > 0.5f;
    }
    unsigned bits = (bin[0]||bin[1]) ? 0u : 1u;
    if (bin[0]) bits |= 2u;
    if (bin[1]) bits |= 4u;
    allowed[s] = bits;
  } else {
    int idx = (bid-220)*256 + threadIdx.x;   // over 3*128*8*64 = 196608
    if (idx >= 3*128*8*64) return;
    int d   = idx & 63;
    int h   = (idx >> 6) & 7;
    int p   = (idx >> 9) & 127;
    int seg = idx >> 16;
    int low = idx & 65535;                   // (p*8+h)*64+d
    float kv_, vv_;
    if (seg == 0){ kv_ = k[low];                          vv_ = v[low]; }
    else         { kv_ = rk[(size_t)(seg-1)*65536 + low]; vv_ = rv[(size_t)(seg-1)*65536 + low]; }
    const int kk = seg*128 + p;              // key index within head, 0..383
    // K fragment placement
    {
      const int f  = d >> 4, hi = (d >> 3) & 1, j = d & 7;
      Kb[(size_t)h*24576 + ((kk>>5)*4 + f)*512
         + (hi*32 + (kk&31))*8 + j] = (unsigned short)bf16bits(kv_);
    }
    // V fragment placement (sigma-permuted key slot)
    {
      const int kap = kk & 31;
      const int kh  = kap >> 4, rem = kap & 15;
      const int hi  = (rem >> 2) & 1;
      const int e   = (rem & 3) + 4*(rem >> 3);
      const int dblk = d >> 5;
      VT[(size_t)h*24576 + ((kk>>5)*4 + dblk*2 + kh)*512
         + (hi*32 + (d&31))*8 + e] = (unsigned short)bf16bits(vv_);
    }
  }
}

// ---------------- fused regional+base attention, pure-TLP path ----------------
// ROUND 16: NO LDS, NO BARRIER, NO FENCES. Rounds 8-15 (eight structures,
// 106-128us) showed the limiter is per-wave dependency latency with only
// ~2 effective waves/SIMD; LDS staging forced a block-wide __syncthreads
// (coupling 4 waves to the slowest staging drain, 55 block-generations/CU)
// while buying nothing: K+V = 768KB total, fully L2-resident. This kernel
// reads BOTH K and V fragments from L2 at use (identity-lane 1KB chunks,
// coalesced dwordx4); every wave is fully independent. LDS=0 and VGPR<=128
// -> 4 waves/SIMD residency actually usable (no barrier alignment), the
// implicit-TLP overlap regime. L2 demand ~1.3GB over the kernel (~18TB/s,
// half the ceiling); L1 gets cross-wave reuse of the shared 96KB stream.
// 256 threads (4 waves) per (head, 128-query chunk); 32 queries per wave
// (32x32x16 MFMA); sigma-permuted V so score C regs ARE the PV B-operand;
// four f32x16 accumulator sets in regs; region mask folded into exp2 bias.
__global__ __launch_bounds__(256)
void attn_kernel(const float* __restrict__ q,
                 const unsigned* __restrict__ allowed,
                 const unsigned short* __restrict__ Kb,
                 const unsigned short* __restrict__ VT,
                 float* __restrict__ out){
  const int h    = blockIdx.y;
  const int wave = threadIdx.x >> 6;
  const int lane = threadIdx.x & 63;
  const int qc   = lane & 31;        // query col
  const int hi   = lane >> 5;        // lane half

  const int s = blockIdx.x*128 + wave*32 + qc;

  // ---- q load -> 4 bf16 frags (lane holds q[s][f*16 + 8*hi + e])
  const unsigned ab = allowed[s];
  const float* qp = q + ((size_t)s*8 + h)*64 + hi*8;
  short8 qf0, qf1, qf2, qf3;
  {
    f32x4 a, b;
    a = *(const f32x4*)(qp);      b = *(const f32x4*)(qp+4);
    #pragma unroll
    for (int j=0;j<4;j++){ qf0[j]=bf16bits(a[j]); qf0[4+j]=bf16bits(b[j]); }
    a = *(const f32x4*)(qp+16);   b = *(const f32x4*)(qp+20);
    #pragma unroll
    for (int j=0;j<4;j++){ qf1[j]=bf16bits(a[j]); qf1[4+j]=bf16bits(b[j]); }
    a = *(const f32x4*)(qp+32);   b = *(const f32x4*)(qp+36);
    #pragma unroll
    for (int j=0;j<4;j++){ qf2[j]=bf16bits(a[j]); qf2[4+j]=bf16bits(b[j]); }
    a = *(const f32x4*)(qp+48);   b = *(const f32x4*)(qp+52);
    #pragma unroll
    for (int j=0;j<4;j++){ qf3[j]=bf16bits(a[j]); qf3[4+j]=bf16bits(b[j]); }
  }

  const char* kgf = (const char*)Kb + (size_t)h*49152 + lane*16;  // K frags (L2)
  const char* vgf = (const char*)VT + (size_t)h*49152 + lane*16;  // V frags (L2)

// one 32-key chunk: load 4 K frags + 4 V frags from L2, 4 score MFMAs,
// exp2(fma, mask in bias) -> pf0/pf1 (PV B-frags via sigma) -> 4 PV MFMAs
#define CHUNK(kc, LSUM, BIAS, A0, A1)                                 \
  {                                                                   \
    short8 kf0 = *(const short8*)(kgf + ((kc)*4+0)*1024);             \
    short8 kf1 = *(const short8*)(kgf + ((kc)*4+1)*1024);             \
    short8 kf2 = *(const short8*)(kgf + ((kc)*4+2)*1024);             \
    short8 kf3 = *(const short8*)(kgf + ((kc)*4+3)*1024);             \
    short8 v0  = *(const short8*)(vgf + ((kc)*4+0)*1024);             \
    short8 v1  = *(const short8*)(vgf + ((kc)*4+1)*1024);             \
    short8 v2  = *(const short8*)(vgf + ((kc)*4+2)*1024);             \
    short8 v3  = *(const short8*)(vgf + ((kc)*4+3)*1024);             \
    f32x16 sa = {0,0,0,0,0,0,0,0,0,0,0,0,0,0,0,0};                    \
    sa = MFMA32(kf0, qf0, sa);                                        \
    sa = MFMA32(kf1, qf1, sa);                                        \
    sa = MFMA32(kf2, qf2, sa);                                        \
    sa = MFMA32(kf3, qf3, sa);                                        \
    short8 pf0, pf1;                                                  \
    _Pragma("unroll")                                                 \
    for (int r=0;r<8;r++){                                            \
      float e0 = EXP_SCORE(sa[r],   BIAS); LSUM += e0; pf0[r] = bf16bits(e0); \
      float e1 = EXP_SCORE(sa[8+r], BIAS); LSUM += e1; pf1[r] = bf16bits(e1); \
    }                                                                 \
    A0 = MFMA32(v0, pf0, A0);                                         \
    A0 = MFMA32(v1, pf1, A0);                                         \
    A1 = MFMA32(v2, pf0, A1);                                         \
    A1 = MFMA32(v3, pf1, A1);                                         \
  }

  const float bias1 = ((ab>>1)&1u) ? EXP_C2 : -3.0e38f;  // region 0 (chunks 4-7)
  const float bias2 = ((ab>>2)&1u) ? EXP_C2 : -3.0e38f;  // region 1 (chunks 8-11)

  float lb = 0.f, lr = 0.f;
  f32x16 aB0 = {0,0,0,0,0,0,0,0,0,0,0,0,0,0,0,0};
  f32x16 aB1 = {0,0,0,0,0,0,0,0,0,0,0,0,0,0,0,0};
  f32x16 aR0 = {0,0,0,0,0,0,0,0,0,0,0,0,0,0,0,0};
  f32x16 aR1 = {0,0,0,0,0,0,0,0,0,0,0,0,0,0,0,0};

  // ---- base pass (keys 0-127) -> aB*
  CHUNK(0, lb, EXP_C2, aB0, aB1);
  CHUNK(1, lb, EXP_C2, aB0, aB1);
  CHUNK(2, lb, EXP_C2, aB0, aB1);
  CHUNK(3, lb, EXP_C2, aB0, aB1);

  // ---- regional pass (keys 128-383) -> aR*
  CHUNK(4,  lr, bias1, aR0, aR1);
  CHUNK(5,  lr, bias1, aR0, aR1);
  CHUNK(6,  lr, bias1, aR0, aR1);
  CHUNK(7,  lr, bias1, aR0, aR1);
  CHUNK(8,  lr, bias2, aR0, aR1);
  CHUNK(9,  lr, bias2, aR0, aR1);
  CHUNK(10, lr, bias2, aR0, aR1);
  CHUNK(11, lr, bias2, aR0, aR1);

  // ---- row sums: lanes l and l^32 hold the two key-halves of one query
  lb += __shfl_xor(lb, 32);
  lr += __shfl_xor(lr, 32);

  const float invb = 0.5f/lb;
  const float lreg = ((ab&1u)? lb : 0.f) + lr;
  const float invr = 0.5f/lreg;
  const float cA   = invb + ((ab&1u)? invr : 0.f);

  // ---- combine and store:
  // reg R=g*4+r of dblk -> d = dblk*32 + 8*g + 4*hi + r  (16B f32x4 stores)
  float* ob = out + (size_t)s*512 + h*64 + hi*4;
  #pragma unroll
  for (int g=0; g<4; ++g){
    f32x4 o0, o1;
    #pragma unroll
    for (int r=0;r<4;r++){
      o0[r] = aB0[g*4+r]*cA + aR0[g*4+r]*invr;
      o1[r] = aB1[g*4+r]*cA + aR1[g*4+r]*invr;
    }
    *(f32x4*)(ob + g*8)      = o0;   // dblk 0
    *(f32x4*)(ob + 32 + g*8) = o1;   // dblk 1
  }
}

extern "C" void kernel_launch(void* const* d_in, const int* in_sizes, int n_in,
                              void* d_out, int out_size, void* d_ws, size_t ws_size,
                              hipStream_t stream) {
  const float* q  = (const float*)d_in[0];
  const float* k  = (const float*)d_in[1];
  const float* v  = (const float*)d_in[2];
  const float* rk = (const float*)d_in[3];
  const float* rv = (const float*)d_in[4];
  const float* rm = (const float*)d_in[5];
  float* out = (float*)d_out;

  char* ws = (char*)d_ws;
  unsigned*       allowed = (unsigned*)ws;                           // 56320*4   = 225280 B
  unsigned short* Kb      = (unsigned short*)(ws + 225280);          // 8*3*128*64*2 = 393216 B
  unsigned short* VT      = (unsigned short*)(ws + 225280 + 393216); // 393216 B

  prep_kernel<<<988, 256, 0, stream>>>(rm, k, v, rk, rv, allowed, Kb, VT);
  dim3 grid(440, 8);
  attn_kernel<<<grid, 256, 0, stream>>>(q, allowed, Kb, VT, out);
}

// Round 17
// 261.754 us; speedup vs baseline: 1.0041x; 1.0041x over previous
//
#include <hip/hip_runtime.h>

typedef short short8  __attribute__((ext_vector_type(8)));
typedef float f32x4   __attribute__((ext_vector_type(4)));
typedef float f32x16  __attribute__((ext_vector_type(16)));

#define MFMA32(A,B,C) __builtin_amdgcn_mfma_f32_32x32x16_bf16((A),(B),(C),0,0,0)

__device__ __forceinline__ short bf16bits(float f){
  return (short)__builtin_bit_cast(unsigned short, static_cast<__bf16>(f));
}

// exp(s*0.125 - 8) = exp2(s*0.125*log2e - 8*log2e): one v_fma + v_exp.
// Region mask folded into BIAS: -3e38 -> exp2 == 0 exactly.
#define EXP_SCORE(s, BIAS) __builtin_amdgcn_exp2f(__builtin_fmaf((s), 0.18033688011112042f, (BIAS)))
#define EXP_C2 (-11.541560327111707f)

// ---------------- fused preprocessing ----------------
// blocks [0,220): mask preprocessing  (region_masks -> allowed bits)
// blocks [220,988): K/V repack to bf16 for the 32x32x16 MFMA path.
// All fragment chunks are 1KB = 64 lanes x 16B, lane l at offset l*16
// (fully-coalesced global_load_dwordx4 by construction).
//   K chunk (kc=key/32, f=d/16): lane = ((d>>3)&1)*32 + (key&31),
//     elem j = d&7  -> holds K[key][d = f*16 + 8*hi + j].
//   V chunk (kc, dblk=d/32, kh): key slot sigma-permuted so the score
//     MFMA's C register file IS the PV B-operand (no P anywhere):
//     C row formula row=(r&3)+8*(r>>2)+4*hi  =>  slot (kh,hi,e) must hold
//     key kappa = 16*kh + (e&3) + 8*(e>>2) + 4*hi. Inverse (given kappa):
//     kh=kappa>>4; rem=kappa&15; hi=(rem>>2)&1; e=(rem&3)+4*(rem>>3).
// (Layouts verified on hardware in rounds 14-16: passed, same absmax.)
__global__ __launch_bounds__(256) void prep_kernel(const float* __restrict__ rm,
                                                   const float* __restrict__ k,
                                                   const float* __restrict__ v,
                                                   const float* __restrict__ rk,
                                                   const float* __restrict__ rv,
                                                   unsigned* __restrict__ allowed,
                                                   unsigned short* __restrict__ Kb,
                                                   unsigned short* __restrict__ VT){
  const int bid = blockIdx.x;
  if (bid < 220){
    int s = bid*256 + threadIdx.x;
    if (s >= 56320) return;
    int t = s / 3520;
    int rem = s - t*3520;
    int i = rem / 80;
    int j = rem - i*80;
    int y = 2*i, x = 2*j;
    bool bin[2];
    #pragma unroll
    for (int r=0;r<2;r++){
      const float* base = rm + (size_t)r*121*88*160;
      float acc;
      if (t == 0){
        const float* p0 = base + (size_t)(0*88 + y)*160 + x;
        acc = 0.25f*(p0[0]+p0[1]+p0[160]+p0[161]);
      } else {
        const float* pa = base + (size_t)((8*t-4)*88 + y)*160 + x;
        const float* pb = base + (size_t)((8*t-3)*88 + y)*160 + x;
        acc = 0.125f*(pa[0]+pa[1]+pa[160]+pa[161] + pb[0]+pb[1]+pb[160]+pb[161]);
      }
      bin[r] = acc > 0.5f;
    }
    unsigned bits = (bin[0]||bin[1]) ? 0u : 1u;
    if (bin[0]) bits |= 2u;
    if (bin[1]) bits |= 4u;
    allowed[s] = bits;
  } else {
    int idx = (bid-220)*256 + threadIdx.x;   // over 3*128*8*64 = 196608
    if (idx >= 3*128*8*64) return;
    int d   = idx & 63;
    int h   = (idx >> 6) & 7;
    int p   = (idx >> 9) & 127;
    int seg = idx >> 16;
    int low = idx & 65535;                   // (p*8+h)*64+d
    float kv_, vv_;
    if (seg == 0){ kv_ = k[low];                          vv_ = v[low]; }
    else         { kv_ = rk[(size_t)(seg-1)*65536 + low]; vv_ = rv[(size_t)(seg-1)*65536 + low]; }
    const int kk = seg*128 + p;              // key index within head, 0..383
    // K fragment placement
    {
      const int f  = d >> 4, hi = (d >> 3) & 1, j = d & 7;
      Kb[(size_t)h*24576 + ((kk>>5)*4 + f)*512
         + (hi*32 + (kk&31))*8 + j] = (unsigned short)bf16bits(kv_);
    }
    // V fragment placement (sigma-permuted key slot)
    {
      const int kap = kk & 31;
      const int kh  = kap >> 4, rem = kap & 15;
      const int hi  = (rem >> 2) & 1;
      const int e   = (rem & 3) + 4*(rem >> 3);
      const int dblk = d >> 5;
      VT[(size_t)h*24576 + ((kk>>5)*4 + dblk*2 + kh)*512
         + (hi*32 + (d&31))*8 + e] = (unsigned short)bf16bits(vv_);
    }
  }
}

// ---------------- fused regional+base attention, pure-TLP + deep prefetch ----
// ROUND 17: r16 (no LDS, no barrier, fully independent waves) + the one
// mechanism that measurably worked (r10, -11%): fence-pinned register
// prefetch — now DOUBLE-BUFFERED over both K and V. Buffers A/B alternate;
// the loads for chunk p+2 issue right after chunk p consumes its buffer,
// giving a full-chunk window (~600-700cy) to cover L2/L3 latency (r16
// loaded at-use: ~104 serialized round-trips -> 13us wave lifetime vs
// ~1.5us busy). sched_barrier(0x38F) pins VMEM issue order while letting
// VALU/MFMA cross for cross-chunk ILP. Cost: 64 in-flight VGPRs (~170
// total, 3 waves/SIMD cap — measured residency was 1.6, so no loss).
// 256 threads (4 waves) per (head, 128-query chunk); 32 queries per wave;
// sigma-permuted V so score C regs ARE the PV B-operand (no P buffer);
// four f32x16 acc sets in regs; region mask folded into exp2 bias.
__global__ __launch_bounds__(256)
void attn_kernel(const float* __restrict__ q,
                 const unsigned* __restrict__ allowed,
                 const unsigned short* __restrict__ Kb,
                 const unsigned short* __restrict__ VT,
                 float* __restrict__ out){
  const int h    = blockIdx.y;
  const int wave = threadIdx.x >> 6;
  const int lane = threadIdx.x & 63;
  const int qc   = lane & 31;        // query col
  const int hi   = lane >> 5;        // lane half

  const int s = blockIdx.x*128 + wave*32 + qc;

  const char* kgf = (const char*)Kb + (size_t)h*49152 + lane*16;  // K frags (L2)
  const char* vgf = (const char*)VT + (size_t)h*49152 + lane*16;  // V frags (L2)

  // ---- q + mask loads issue first (oldest in vmcnt order: their waits
  //      don't drain the K/V stream behind them)
  const unsigned ab = allowed[s];
  const float* qp = q + ((size_t)s*8 + h)*64 + hi*8;
  f32x4 qa0 = *(const f32x4*)(qp);      f32x4 qb0 = *(const f32x4*)(qp+4);
  f32x4 qa1 = *(const f32x4*)(qp+16);   f32x4 qb1 = *(const f32x4*)(qp+20);
  f32x4 qa2 = *(const f32x4*)(qp+32);   f32x4 qb2 = *(const f32x4*)(qp+36);
  f32x4 qa3 = *(const f32x4*)(qp+48);   f32x4 qb3 = *(const f32x4*)(qp+52);

  // ---- double-buffered K/V fragment prefetch (named regs, compile-time)
  short8 kA0,kA1,kA2,kA3, vA0,vA1,vA2,vA3;
  short8 kB0,kB1,kB2,kB3, vB0,vB1,vB2,vB3;
#define LOAD_A(kc)                                                    \
  kA0 = *(const short8*)(kgf + ((kc)*4+0)*1024);                      \
  kA1 = *(const short8*)(kgf + ((kc)*4+1)*1024);                      \
  kA2 = *(const short8*)(kgf + ((kc)*4+2)*1024);                      \
  kA3 = *(const short8*)(kgf + ((kc)*4+3)*1024);                      \
  vA0 = *(const short8*)(vgf + ((kc)*4+0)*1024);                      \
  vA1 = *(const short8*)(vgf + ((kc)*4+1)*1024);                      \
  vA2 = *(const short8*)(vgf + ((kc)*4+2)*1024);                      \
  vA3 = *(const short8*)(vgf + ((kc)*4+3)*1024);                      \
  __builtin_amdgcn_sched_barrier(0x38F);  /* pin VMEM issue order */
#define LOAD_B(kc)                                                    \
  kB0 = *(const short8*)(kgf + ((kc)*4+0)*1024);                      \
  kB1 = *(const short8*)(kgf + ((kc)*4+1)*1024);                      \
  kB2 = *(const short8*)(kgf + ((kc)*4+2)*1024);                      \
  kB3 = *(const short8*)(kgf + ((kc)*4+3)*1024);                      \
  vB0 = *(const short8*)(vgf + ((kc)*4+0)*1024);                      \
  vB1 = *(const short8*)(vgf + ((kc)*4+1)*1024);                      \
  vB2 = *(const short8*)(vgf + ((kc)*4+2)*1024);                      \
  vB3 = *(const short8*)(vgf + ((kc)*4+3)*1024);                      \
  __builtin_amdgcn_sched_barrier(0x38F);

// one 32-key chunk from buffer X: 4 score MFMAs -> exp2(fma, mask in
// bias) -> pf0/pf1 (PV B-frags via sigma) -> 4 PV MFMAs
#define CHUNK_X(K0,K1,K2,K3,V0,V1,V2,V3, LSUM, BIAS, A0, A1)          \
  {                                                                   \
    f32x16 sa = {0,0,0,0,0,0,0,0,0,0,0,0,0,0,0,0};                    \
    sa = MFMA32(K0, qf0, sa);                                         \
    sa = MFMA32(K1, qf1, sa);                                         \
    sa = MFMA32(K2, qf2, sa);                                         \
    sa = MFMA32(K3, qf3, sa);                                         \
    short8 pf0, pf1;                                                  \
    _Pragma("unroll")                                                 \
    for (int r=0;r<8;r++){                                            \
      float e0 = EXP_SCORE(sa[r],   BIAS); LSUM += e0; pf0[r] = bf16bits(e0); \
      float e1 = EXP_SCORE(sa[8+r], BIAS); LSUM += e1; pf1[r] = bf16bits(e1); \
    }                                                                 \
    A0 = MFMA32(V0, pf0, A0);                                         \
    A0 = MFMA32(V1, pf1, A0);                                         \
    A1 = MFMA32(V2, pf0, A1);                                         \
    A1 = MFMA32(V3, pf1, A1);                                         \
  }
#define CHUNK_A(LSUM, BIAS, A0, A1) CHUNK_X(kA0,kA1,kA2,kA3,vA0,vA1,vA2,vA3,LSUM,BIAS,A0,A1)
#define CHUNK_B(LSUM, BIAS, A0, A1) CHUNK_X(kB0,kB1,kB2,kB3,vB0,vB1,vB2,vB3,LSUM,BIAS,A0,A1)

  // ---- prologue: fill both buffers (chunks 0 and 1 in flight)
  LOAD_A(0);
  LOAD_B(1);

  // ---- q -> bf16 frags (overlaps the in-flight K/V stream)
  short8 qf0, qf1, qf2, qf3;
  #pragma unroll
  for (int j=0;j<4;j++){
    qf0[j]=bf16bits(qa0[j]); qf0[4+j]=bf16bits(qb0[j]);
    qf1[j]=bf16bits(qa1[j]); qf1[4+j]=bf16bits(qb1[j]);
    qf2[j]=bf16bits(qa2[j]); qf2[4+j]=bf16bits(qb2[j]);
    qf3[j]=bf16bits(qa3[j]); qf3[4+j]=bf16bits(qb3[j]);
  }

  const float bias1 = ((ab>>1)&1u) ? EXP_C2 : -3.0e38f;  // region 0 (chunks 4-7)
  const float bias2 = ((ab>>2)&1u) ? EXP_C2 : -3.0e38f;  // region 1 (chunks 8-11)

  float lb = 0.f, lr = 0.f;
  f32x16 aB0 = {0,0,0,0,0,0,0,0,0,0,0,0,0,0,0,0};
  f32x16 aB1 = {0,0,0,0,0,0,0,0,0,0,0,0,0,0,0,0};
  f32x16 aR0 = {0,0,0,0,0,0,0,0,0,0,0,0,0,0,0,0};
  f32x16 aR1 = {0,0,0,0,0,0,0,0,0,0,0,0,0,0,0,0};

  // ---- steady state: consume one buffer, immediately refill it 2 ahead
  CHUNK_A(lb, EXP_C2, aB0, aB1);  LOAD_A(2);    // base pass (keys 0-127)
  CHUNK_B(lb, EXP_C2, aB0, aB1);  LOAD_B(3);
  CHUNK_A(lb, EXP_C2, aB0, aB1);  LOAD_A(4);
  CHUNK_B(lb, EXP_C2, aB0, aB1);  LOAD_B(5);
  CHUNK_A(lr, bias1,  aR0, aR1);  LOAD_A(6);    // region 0 (keys 128-255)
  CHUNK_B(lr, bias1,  aR0, aR1);  LOAD_B(7);
  CHUNK_A(lr, bias1,  aR0, aR1);  LOAD_A(8);
  CHUNK_B(lr, bias1,  aR0, aR1);  LOAD_B(9);
  CHUNK_A(lr, bias2,  aR0, aR1);  LOAD_A(10);   // region 1 (keys 256-383)
  CHUNK_B(lr, bias2,  aR0, aR1);  LOAD_B(11);
  CHUNK_A(lr, bias2,  aR0, aR1);
  CHUNK_B(lr, bias2,  aR0, aR1);

  // ---- row sums: lanes l and l^32 hold the two key-halves of one query
  lb += __shfl_xor(lb, 32);
  lr += __shfl_xor(lr, 32);

  const float invb = 0.5f/lb;
  const float lreg = ((ab&1u)? lb : 0.f) + lr;
  const float invr = 0.5f/lreg;
  const float cA   = invb + ((ab&1u)? invr : 0.f);

  // ---- combine and store:
  // reg R=g*4+r of dblk -> d = dblk*32 + 8*g + 4*hi + r  (16B f32x4 stores)
  float* ob = out + (size_t)s*512 + h*64 + hi*4;
  #pragma unroll
  for (int g=0; g<4; ++g){
    f32x4 o0, o1;
    #pragma unroll
    for (int r=0;r<4;r++){
      o0[r] = aB0[g*4+r]*cA + aR0[g*4+r]*invr;
      o1[r] = aB1[g*4+r]*cA + aR1[g*4+r]*invr;
    }
    *(f32x4*)(ob + g*8)      = o0;   // dblk 0
    *(f32x4*)(ob + 32 + g*8) = o1;   // dblk 1
  }
}

extern "C" void kernel_launch(void* const* d_in, const int* in_sizes, int n_in,
                              void* d_out, int out_size, void* d_ws, size_t ws_size,
                              hipStream_t stream) {
  const float* q  = (const float*)d_in[0];
  const float* k  = (const float*)d_in[1];
  const float* v  = (const float*)d_in[2];
  const float* rk = (const float*)d_in[3];
  const float* rv = (const float*)d_in[4];
  const float* rm = (const float*)d_in[5];
  float* out = (float*)d_out;

  char* ws = (char*)d_ws;
  unsigned*       allowed = (unsigned*)ws;                           // 56320*4   = 225280 B
  unsigned short* Kb      = (unsigned short*)(ws + 225280);          // 8*3*128*64*2 = 393216 B
  unsigned short* VT      = (unsigned short*)(ws + 225280 + 393216); // 393216 B

  prep_kernel<<<988, 256, 0, stream>>>(rm, k, v, rk, rv, allowed, Kb, VT);
  dim3 grid(440, 8);
  attn_kernel<<<grid, 256, 0, stream>>>(q, allowed, Kb, VT, out);
}